// Round 18
// baseline (328.870 us; speedup 1.0000x reference)
//
#include <hip/hip_runtime.h>
#include <hip/hip_bf16.h>
#include <stdint.h>

#define T_TOK 4096
#define DIM   1024
#define HID   4096
#define NEXP  8
#define NSLOT (T_TOK * 2)
#define KSPLIT 2
#define KS_LEN (HID / KSPLIT)
#define MAXMT 72                 // max sum of ceil(cnt_e/128)
#define GRID1 (8 * 4 * MAXMT)    // 2304 gemm1 job slots
#define GRID2 (8 * 2 * MAXMT)    // 1152 gemm2 job slots
#define RT_BLKS 1024             // router blocks (first, so they start immediately)
#define RP1_BLKS 2048            // w1 repack: 8 e x 16 ks x 16 nc
#define RP2_BLKS 2048            // w2 repack: 8 e x 64 ks x 4 nc

typedef __attribute__((ext_vector_type(8))) short bf16x8;
typedef __attribute__((ext_vector_type(4))) float f32x4;

#define AS1(p) ((const __attribute__((address_space(1))) void*)(p))
#define AS3(p) ((__attribute__((address_space(3))) void*)(p))

static __device__ __forceinline__ unsigned short f2bf(float f) {
    unsigned int u = __float_as_uint(f);
    unsigned int r = (u + 0x7fffu + ((u >> 16) & 1u)) >> 16;
    return (unsigned short)r;
}

static __device__ __forceinline__ f32x4 mfma16(bf16x8 a, bf16x8 b, f32x4 c) {
    return __builtin_amdgcn_mfma_f32_16x16x32_bf16(a, b, c, 0, 0, 0);
}

// ---------------- repack one [64k x 256n] slab into 2 pre-swizzled 16KB GEMM tiles --------
// Register-assembled: wave w owns gc in {w, w+4}; per lane, 8 x float4 down the k-column
// of its n-quad (each load instr = 1KB coalesced wave segment), chunks built in registers,
// written as 16B bf16x8 direct to global. No LDS, no barriers, no bank conflicts.
// Tile byte r*128 + (gc^(r&7))*16 + kp*2 holds element (k = gc*8+kp, n-row r). (verified fmt)
static __device__ __forceinline__ void repack_slab(
    const float* __restrict__ src, int N, char* __restrict__ dst0, size_t ntStride) {
    const int lane = threadIdx.x & 63;
    const int w = threadIdx.x >> 6;
#pragma unroll
    for (int h = 0; h < 2; ++h) {
        const int gc = w + h * 4;
        f32x4 f[8];
#pragma unroll
        for (int kp = 0; kp < 8; ++kp)
            f[kp] = *(const f32x4*)(src + (size_t)(gc * 8 + kp) * N + lane * 4);
#pragma unroll
        for (int j = 0; j < 4; ++j) {
            int nl = lane * 4 + j;
            int nt_sub = nl >> 7, r = nl & 127;
            bf16x8 v = {(short)f2bf(f[0][j]), (short)f2bf(f[1][j]),
                        (short)f2bf(f[2][j]), (short)f2bf(f[3][j]),
                        (short)f2bf(f[4][j]), (short)f2bf(f[5][j]),
                        (short)f2bf(f[6][j]), (short)f2bf(f[7][j])};
            *(bf16x8*)(dst0 + nt_sub * ntStride + r * 128 + ((gc ^ (r & 7)) << 4)) = v;
        }
    }
}

// ---------------- fused: router (NO atomics, first) + repack w1 ----------------

__global__ __launch_bounds__(256) void pre_kernel(
    const float* __restrict__ w1, char* __restrict__ w1blk,
    const float* __restrict__ x, const float* __restrict__ rw,
    const float* __restrict__ rb, unsigned short* __restrict__ xb,
    int* __restrict__ top_i, float* __restrict__ top_w) {
    const int bid = blockIdx.x;
    if (bid >= RT_BLKS) {
        // repack w1: rbid = ((e*16 + ks)*16 + nc)
        int rbid = bid - RT_BLKS;
        int nc = rbid & 15, ks = (rbid >> 4) & 15, e = rbid >> 8;
        const float* src = w1 + ((size_t)e * DIM + ks * 64) * HID + nc * 256;
        char* dst0 = w1blk + (((size_t)e * 32 + nc * 2) * 16 + ks) * 16384;
        repack_slab(src, HID, dst0, (size_t)16 * 16384);
        return;
    }
    // router: one wave per token (fused x->bf16 conversion); atomic-free
    int t = bid * 4 + (threadIdx.x >> 6);
    int lane = threadIdx.x & 63;
    const float4* xr = (const float4*)(x + (size_t)t * DIM);
    float acc[NEXP];
#pragma unroll
    for (int e = 0; e < NEXP; ++e) acc[e] = 0.f;
#pragma unroll
    for (int i = 0; i < 4; ++i) {
        int vidx = lane + i * 64;
        float4 v = xr[vidx];
        ushort4 o;
        o.x = f2bf(v.x); o.y = f2bf(v.y); o.z = f2bf(v.z); o.w = f2bf(v.w);
        ((ushort4*)xb)[(size_t)t * 256 + vidx] = o;
        const float4* wr = (const float4*)(rw + (size_t)vidx * 4 * NEXP);
        float xs[4] = {v.x, v.y, v.z, v.w};
#pragma unroll
        for (int j = 0; j < 4; ++j) {
            float4 wlo = wr[j * 2 + 0], whi = wr[j * 2 + 1];
            acc[0] += xs[j] * wlo.x; acc[1] += xs[j] * wlo.y;
            acc[2] += xs[j] * wlo.z; acc[3] += xs[j] * wlo.w;
            acc[4] += xs[j] * whi.x; acc[5] += xs[j] * whi.y;
            acc[6] += xs[j] * whi.z; acc[7] += xs[j] * whi.w;
        }
    }
#pragma unroll
    for (int e = 0; e < NEXP; ++e) {
#pragma unroll
        for (int off = 32; off; off >>= 1) acc[e] += __shfl_xor(acc[e], off);
    }
    if (lane == 0) {
        float l[NEXP];
#pragma unroll
        for (int e = 0; e < NEXP; ++e) l[e] = acc[e] + rb[e];
        float best = -1e30f; int bi = 0;
#pragma unroll
        for (int e = 0; e < NEXP; ++e) if (l[e] > best) { best = l[e]; bi = e; }
        float best2 = -1e30f; int bi2 = 0;
#pragma unroll
        for (int e = 0; e < NEXP; ++e) { if (e == bi) continue; if (l[e] > best2) { best2 = l[e]; bi2 = e; } }
        float w0 = 1.f / (1.f + expf(best2 - best));
        top_i[t * 2] = bi;  top_i[t * 2 + 1] = bi2;
        top_w[t * 2] = w0;  top_w[t * 2 + 1] = 1.f - w0;
    }
}

// ---------------- plan: histogram + scan + slot assignment, ONE block, LDS atomics --------

__global__ __launch_bounds__(1024) void plan_kernel(
    const int* __restrict__ top_i, const float* __restrict__ top_w,
    int* __restrict__ counts, int* __restrict__ offsets, int* __restrict__ tile_start,
    int* __restrict__ row_token, float* __restrict__ row_w, int* __restrict__ slot_of) {
    __shared__ int hist[NEXP];
    __shared__ int offs[NEXP];
    __shared__ int curs[NEXP];
    const int tid = threadIdx.x;
    if (tid < NEXP) hist[tid] = 0;
    __syncthreads();
    int my_e[NSLOT / 1024];
#pragma unroll
    for (int c = 0; c < NSLOT / 1024; ++c) {
        int i = c * 1024 + tid;
        my_e[c] = top_i[i];
        atomicAdd(&hist[my_e[c]], 1);
    }
    __syncthreads();
    if (tid == 0) {
        int o = 0, t = 0;
#pragma unroll
        for (int e = 0; e < NEXP; ++e) {
            offs[e] = o; curs[e] = 0;
            counts[e] = hist[e];
            offsets[e] = o;
            tile_start[e] = t;
            t += (hist[e] + 127) >> 7;
            o += hist[e];
        }
        tile_start[NEXP] = t;
    }
    __syncthreads();
#pragma unroll
    for (int c = 0; c < NSLOT / 1024; ++c) {
        int i = c * 1024 + tid;
        int e = my_e[c];
        int s = atomicAdd(&curs[e], 1);
        int g = offs[e] + s;
        row_token[g] = i >> 1;
        row_w[g] = top_w[i];
        slot_of[i] = g;
    }
}

// ---------------- fused: GEMM1 (blocked-tile B) + repack w2 ----------------

__global__ __launch_bounds__(256, 4) void g1_kernel(
    const unsigned short* __restrict__ xb,    // [T][DIM] bf16
    const char* __restrict__ w1blk,           // blocked tiles
    const float* __restrict__ b1,             // [E][HID]
    const int* __restrict__ row_token, const int* __restrict__ offsets,
    const int* __restrict__ counts, const int* __restrict__ ts,
    unsigned short* __restrict__ h_ws,        // [NSLOT][HID] bf16
    const float* __restrict__ w2, char* __restrict__ w2blk) {
    __shared__ __align__(16) char smem[32768];
    const int bid = blockIdx.x;
    if (bid >= GRID1) {
        // repack w2: r = ((e*64 + ks)*4 + nc)
        int r = bid - GRID1;
        int nc = r & 3, ks = (r >> 2) & 63, e = r >> 8;
        const float* src = w2 + ((size_t)e * HID + ks * 64) * DIM + nc * 256;
        char* dst0 = w2blk + (((size_t)e * 8 + nc * 2) * 64 + ks) * 16384;
        repack_slab(src, DIM, dst0, (size_t)64 * 16384);
        return;
    }
    const int xcd = bid & 7, s = bid >> 3;
    if (s >= 4 * ts[NEXP]) return;
    int e = 0;
#pragma unroll
    for (int k = 1; k < NEXP; ++k) if (s >= 4 * ts[k]) e = k;
    const int ntile = ts[e + 1] - ts[e];
    const int local = s - 4 * ts[e];
    const int q = local / ntile;              // 0..3
    const int mt = local - q * ntile;
    const int nt = q * 8 + xcd;               // 0..31
    const int cnt = counts[e];
    const int goff = offsets[e];

    unsigned short (*As)[64] = (unsigned short (*)[64])smem;            // 16 KB
    char* Bs = smem + 16384;                                            // 16 KB

    const int tid = threadIdx.x, wid = tid >> 6, lane = tid & 63;
    const int wm = wid >> 1, wn = wid & 1;

    f32x4 acc[4][4];
#pragma unroll
    for (int i = 0; i < 4; ++i)
#pragma unroll
        for (int j = 0; j < 4; ++j) acc[i][j] = (f32x4){0.f, 0.f, 0.f, 0.f};

    const unsigned short* srcA[4];
#pragma unroll
    for (int it = 0; it < 4; ++it) {
        int idx = it * 256 + tid;
        int r = idx >> 3, kg = idx & 7;
        int sk = kg ^ (r & 7);                 // swizzled source chunk
        int rr = mt * 128 + r;
        int tok = row_token[goff + (rr < cnt ? rr : 0)];
        srcA[it] = xb + (size_t)tok * DIM + sk * 8;
    }
    const char* btile = w1blk + (((size_t)e * 32 + nt) * 16) * 16384;

    for (int t = 0; t < 16; ++t) {
        const int k0 = t * 64;
        const char* bsrc = btile + (size_t)t * 16384;
#pragma unroll
        for (int it = 0; it < 4; ++it) {
            __builtin_amdgcn_global_load_lds(AS1(srcA[it] + k0),
                AS3((char*)As + (it * 4 + wid) * 1024), 16, 0, 0);
            __builtin_amdgcn_global_load_lds(AS1(bsrc + (size_t)(it * 256 + tid) * 16),
                AS3(Bs + (it * 4 + wid) * 1024), 16, 0, 0);
        }
        __syncthreads();                       // drains vmcnt: tile ready
#pragma unroll
        for (int kk = 0; kk < 2; ++kk) {
            bf16x8 a[4], b[4];
            int ch = (kk * 4 + (lane >> 4)) ^ (lane & 7);
#pragma unroll
            for (int i = 0; i < 4; ++i) {
                int row = wm * 64 + i * 16 + (lane & 15);
                a[i] = *(const bf16x8*)((const char*)As + row * 128 + ch * 16);
            }
#pragma unroll
            for (int i = 0; i < 4; ++i) {
                int row = wn * 64 + i * 16 + (lane & 15);
                b[i] = *(const bf16x8*)(Bs + row * 128 + ch * 16);
            }
#pragma unroll
            for (int i = 0; i < 4; ++i)
#pragma unroll
                for (int j = 0; j < 4; ++j)
                    acc[i][j] = mfma16(a[i], b[j], acc[i][j]);
        }
        __syncthreads();
    }

    if (mt * 128 + 128 <= cnt) {               // fast path: full tile
#pragma unroll
        for (int j = 0; j < 4; ++j) {
            int n = nt * 128 + wn * 64 + j * 16 + (lane & 15);
            float bias = b1[e * HID + n];
#pragma unroll
            for (int i = 0; i < 4; ++i) {
#pragma unroll
                for (int q2 = 0; q2 < 4; ++q2) {
                    int rr = mt * 128 + wm * 64 + i * 16 + (lane >> 4) * 4 + q2;
                    float v = fmaxf(acc[i][j][q2] + bias, 0.f);
                    h_ws[(size_t)(goff + rr) * HID + n] = f2bf(v);
                }
            }
        }
    } else {
#pragma unroll
        for (int j = 0; j < 4; ++j) {
            int n = nt * 128 + wn * 64 + j * 16 + (lane & 15);
            float bias = b1[e * HID + n];
#pragma unroll
            for (int i = 0; i < 4; ++i) {
#pragma unroll
                for (int q2 = 0; q2 < 4; ++q2) {
                    int rr = mt * 128 + wm * 64 + i * 16 + (lane >> 4) * 4 + q2;
                    if (rr < cnt) {
                        float v = fmaxf(acc[i][j][q2] + bias, 0.f);
                        h_ws[(size_t)(goff + rr) * HID + n] = f2bf(v);
                    }
                }
            }
        }
    }
}

// GEMM2 (split-K, blocked-tile B): y_part[ks][slot][n] = sum_{k in slice} h[slot][k]*w2[k][n]
__global__ __launch_bounds__(256, 4) void gemm2_kernel(
    const unsigned short* __restrict__ h_ws,  // [NSLOT][HID] bf16
    const char* __restrict__ w2blk,           // blocked tiles
    const int* __restrict__ offsets, const int* __restrict__ counts,
    const int* __restrict__ ts,
    float* __restrict__ y_part) {             // [KSPLIT][NSLOT][DIM] f32
    const int bid = blockIdx.x;
    const int xcd = bid & 7, s = bid >> 3;
    if (s >= 2 * ts[NEXP]) return;
    int e = 0;
#pragma unroll
    for (int k = 1; k < NEXP; ++k) if (s >= 2 * ts[k]) e = k;
    const int ntile = ts[e + 1] - ts[e];
    const int local = s - 2 * ts[e];
    const int ks = local / ntile;             // 0..1
    const int mt = local - ks * ntile;
    const int nt = xcd;                       // 0..7
    const int cnt = counts[e];
    const int goff = offsets[e];

    __shared__ __align__(16) char smem[32768];
    unsigned short (*As)[64] = (unsigned short (*)[64])smem;
    char* Bs = smem + 16384;

    const int tid = threadIdx.x, wid = tid >> 6, lane = tid & 63;
    const int wm = wid >> 1, wn = wid & 1;

    f32x4 acc[4][4];
#pragma unroll
    for (int i = 0; i < 4; ++i)
#pragma unroll
        for (int j = 0; j < 4; ++j) acc[i][j] = (f32x4){0.f, 0.f, 0.f, 0.f};

    const unsigned short* srcA[4];
#pragma unroll
    for (int it = 0; it < 4; ++it) {
        int idx = it * 256 + tid;
        int r = idx >> 3, kg = idx & 7;
        int sk = kg ^ (r & 7);
        int rr = mt * 128 + r;
        int g = goff + (rr < cnt ? rr : 0);
        srcA[it] = h_ws + (size_t)g * HID + sk * 8;
    }
    const char* btile = w2blk + (((size_t)e * 8 + nt) * 64 + ks * 32) * 16384;

    const int kbase = ks * KS_LEN;
    for (int t = 0; t < KS_LEN / 64; ++t) {
        const int k0 = kbase + t * 64;
        const char* bsrc = btile + (size_t)t * 16384;
#pragma unroll
        for (int it = 0; it < 4; ++it) {
            __builtin_amdgcn_global_load_lds(AS1(srcA[it] + k0),
                AS3((char*)As + (it * 4 + wid) * 1024), 16, 0, 0);
            __builtin_amdgcn_global_load_lds(AS1(bsrc + (size_t)(it * 256 + tid) * 16),
                AS3(Bs + (it * 4 + wid) * 1024), 16, 0, 0);
        }
        __syncthreads();
#pragma unroll
        for (int kk = 0; kk < 2; ++kk) {
            bf16x8 a[4], b[4];
            int ch = (kk * 4 + (lane >> 4)) ^ (lane & 7);
#pragma unroll
            for (int i = 0; i < 4; ++i) {
                int row = wm * 64 + i * 16 + (lane & 15);
                a[i] = *(const bf16x8*)((const char*)As + row * 128 + ch * 16);
            }
#pragma unroll
            for (int i = 0; i < 4; ++i) {
                int row = wn * 64 + i * 16 + (lane & 15);
                b[i] = *(const bf16x8*)(Bs + row * 128 + ch * 16);
            }
#pragma unroll
            for (int i = 0; i < 4; ++i)
#pragma unroll
                for (int j = 0; j < 4; ++j)
                    acc[i][j] = mfma16(a[i], b[j], acc[i][j]);
        }
        __syncthreads();
    }

    if (mt * 128 + 128 <= cnt) {
#pragma unroll
        for (int j = 0; j < 4; ++j) {
            int n = nt * 128 + wn * 64 + j * 16 + (lane & 15);
#pragma unroll
            for (int i = 0; i < 4; ++i) {
#pragma unroll
                for (int q2 = 0; q2 < 4; ++q2) {
                    int rr = mt * 128 + wm * 64 + i * 16 + (lane >> 4) * 4 + q2;
                    y_part[((size_t)ks * NSLOT + goff + rr) * DIM + n] = acc[i][j][q2];
                }
            }
        }
    } else {
#pragma unroll
        for (int j = 0; j < 4; ++j) {
            int n = nt * 128 + wn * 64 + j * 16 + (lane & 15);
#pragma unroll
            for (int i = 0; i < 4; ++i) {
#pragma unroll
                for (int q2 = 0; q2 < 4; ++q2) {
                    int rr = mt * 128 + wm * 64 + i * 16 + (lane >> 4) * 4 + q2;
                    if (rr < cnt) {
                        y_part[((size_t)ks * NSLOT + goff + rr) * DIM + n] = acc[i][j][q2];
                    }
                }
            }
        }
    }
}

// out[t][d] = w0*(p0[s0]+p1[s0]+b2[e0]) + w1*(p0[s1]+p1[s1]+b2[e1])
__global__ __launch_bounds__(256) void combine_kernel(
    const float* __restrict__ y_part, const int* __restrict__ slot_of,
    const int* __restrict__ top_i, const float* __restrict__ top_w,
    const float* __restrict__ b2, float* __restrict__ out) {
    int i = blockIdx.x * 256 + threadIdx.x;
    int t = i >> 8, c = i & 255;
    int s0 = slot_of[t * 2], s1 = slot_of[t * 2 + 1];
    int e0 = top_i[t * 2],  e1 = top_i[t * 2 + 1];
    float w0 = top_w[t * 2], w1 = top_w[t * 2 + 1];
    const float4* P = (const float4*)y_part;
    float4 p00 = P[(size_t)s0 * 256 + c];
    float4 p01 = P[((size_t)NSLOT + s0) * 256 + c];
    float4 p10 = P[(size_t)s1 * 256 + c];
    float4 p11 = P[((size_t)NSLOT + s1) * 256 + c];
    float4 b0 = ((const float4*)b2)[e0 * 256 + c];
    float4 b1 = ((const float4*)b2)[e1 * 256 + c];
    float4 o;
    o.x = w0 * (p00.x + p01.x + b0.x) + w1 * (p10.x + p11.x + b1.x);
    o.y = w0 * (p00.y + p01.y + b0.y) + w1 * (p10.y + p11.y + b1.y);
    o.z = w0 * (p00.z + p01.z + b0.z) + w1 * (p10.z + p11.z + b1.z);
    o.w = w0 * (p00.w + p01.w + b0.w) + w1 * (p10.w + p11.w + b1.w);
    ((float4*)out)[i] = o;
}

// ---------------- launch ----------------

extern "C" void kernel_launch(void* const* d_in, const int* in_sizes, int n_in,
                              void* d_out, int out_size, void* d_ws, size_t ws_size,
                              hipStream_t stream) {
    const float* x   = (const float*)d_in[0];
    const float* rw  = (const float*)d_in[1];
    const float* rb  = (const float*)d_in[2];
    const float* w1  = (const float*)d_in[3];
    const float* b1  = (const float*)d_in[4];
    const float* w2  = (const float*)d_in[5];
    const float* b2  = (const float*)d_in[6];
    float* out = (float*)d_out;

    char* ws = (char*)d_ws;
    size_t off = 0;
    auto alloc = [&](size_t bytes) { size_t r = off; off = (off + bytes + 255) & ~(size_t)255; return r; };
    unsigned short* xb   = (unsigned short*)(ws + alloc((size_t)T_TOK * DIM * 2));   // 8 MB
    char* w1blk          = ws + alloc((size_t)NEXP * DIM * HID * 2);                  // 64 MB
    char* w2blk          = ws + alloc((size_t)NEXP * HID * DIM * 2);                  // 64 MB
    unsigned short* h_ws = (unsigned short*)(ws + alloc((size_t)NSLOT * HID * 2));   // 64 MB
    int*   top_i         = (int*)(ws + alloc((size_t)NSLOT * 4));
    float* top_w         = (float*)(ws + alloc((size_t)NSLOT * 4));
    int*   slot_of       = (int*)(ws + alloc((size_t)NSLOT * 4));
    int*   row_token     = (int*)(ws + alloc((size_t)NSLOT * 4));
    float* row_w         = (float*)(ws + alloc((size_t)NSLOT * 4));
    char*  ctrl          = ws + alloc(256);
    int* counts     = (int*)(ctrl);
    int* offsets    = (int*)(ctrl + 64);
    int* tile_start = (int*)(ctrl + 128);
    // y_part (64 MB) aliases w1blk: dead once g1 completes; gemm2/combine follow on-stream.
    float* y_part = (float*)w1blk;

    // fused: router (atomic-free, first) + repack w1 (register-assembled blocked tiles)
    pre_kernel<<<RT_BLKS + RP1_BLKS, 256, 0, stream>>>(w1, w1blk, x, rw, rb, xb,
                                                       top_i, top_w);
    // single-block plan: histogram + offsets + slot assignment via LDS atomics
    plan_kernel<<<1, 1024, 0, stream>>>(top_i, top_w, counts, offsets, tile_start,
                                        row_token, row_w, slot_of);

    // fused: gemm1 (blocked B) + repack w2 (consumed by gemm2, next launch)
    g1_kernel<<<GRID1 + RP2_BLKS, 256, 0, stream>>>(xb, w1blk, b1, row_token, offsets,
                                                    counts, tile_start, h_ws, w2, w2blk);
    gemm2_kernel<<<GRID2, 256, 0, stream>>>(h_ws, w2blk, offsets, counts, tile_start, y_part);

    combine_kernel<<<T_TOK * 256 / 256, 256, 0, stream>>>(y_part, slot_of, top_i, top_w, b2, out);
}

// Round 19
// 296.216 us; speedup vs baseline: 1.1102x; 1.1102x over previous
//
#include <hip/hip_runtime.h>
#include <hip/hip_bf16.h>
#include <stdint.h>

#define T_TOK 4096
#define DIM   1024
#define HID   4096
#define NEXP  8
#define NSLOT (T_TOK * 2)
#define KSPLIT 2
#define KS_LEN (HID / KSPLIT)
#define MAXMT 72                 // max sum of ceil(cnt_e/128)
#define GRID1 (8 * 4 * MAXMT)    // 2304 gemm1 job slots
#define GRID2 (8 * 2 * MAXMT)    // 1152 gemm2 job slots
#define RT_BLKS 1024             // router blocks (first, so they start immediately)
#define RP1_BLKS 2048            // w1 repack: 8 e x 16 ks x 16 nc
#define RP2_BLKS 2048            // w2 repack: 8 e x 64 ks x 4 nc

typedef __attribute__((ext_vector_type(8))) short bf16x8;
typedef __attribute__((ext_vector_type(4))) float f32x4;

#define AS1(p) ((const __attribute__((address_space(1))) void*)(p))
#define AS3(p) ((__attribute__((address_space(3))) void*)(p))

static __device__ __forceinline__ unsigned short f2bf(float f) {
    unsigned int u = __float_as_uint(f);
    unsigned int r = (u + 0x7fffu + ((u >> 16) & 1u)) >> 16;
    return (unsigned short)r;
}

static __device__ __forceinline__ f32x4 mfma16(bf16x8 a, bf16x8 b, f32x4 c) {
    return __builtin_amdgcn_mfma_f32_16x16x32_bf16(a, b, c, 0, 0, 0);
}

// ---------------- repack one [64k x 256n] slab into 2 pre-swizzled 16KB GEMM tiles --------
// Fill: lane owns chunk (gc, nl=q*64+lane); 8 scalar fp32 loads (each instr = 256B
// coalesced segment), pack bf16x8, ONE ds_write_b128. Lanes have consecutive r ->
// r&7 covers 0..7 -> chunk cols cover all 8 -> minimum bank aliasing (conflict-free).
// Drain: sequential 16KB global write-out (verified round-17 phase).
// Tile byte r*128 + (gc^(r&7))*16 + kp*2 holds element (k = gc*8+kp, n-row r).
static __device__ __forceinline__ void repack_slab(
    const float* __restrict__ src, int N, char* __restrict__ dst0,
    size_t ntStride, char* smem) {
    const int lane = threadIdx.x & 63;
    const int w = threadIdx.x >> 6;
#pragma unroll
    for (int h = 0; h < 2; ++h) {
        const int gc = w + h * 4;
#pragma unroll
        for (int q = 0; q < 4; ++q) {
            const int nl = q * 64 + lane;
            const int nt_sub = nl >> 7, r = nl & 127;
            const float* p = src + (size_t)(gc * 8) * N + nl;
            bf16x8 v = {(short)f2bf(p[0]),
                        (short)f2bf(p[(size_t)1 * N]),
                        (short)f2bf(p[(size_t)2 * N]),
                        (short)f2bf(p[(size_t)3 * N]),
                        (short)f2bf(p[(size_t)4 * N]),
                        (short)f2bf(p[(size_t)5 * N]),
                        (short)f2bf(p[(size_t)6 * N]),
                        (short)f2bf(p[(size_t)7 * N])};
            *(bf16x8*)(smem + nt_sub * 16384 + r * 128 + ((gc ^ (r & 7)) << 4)) = v;
        }
    }
    __syncthreads();
    const int tid = threadIdx.x;
#pragma unroll
    for (int i = 0; i < 8; ++i) {
        int c = i * 256 + tid;                 // 2048 x 16B
        int nt_sub = c >> 10, chunk = c & 1023;
        *(float4*)(dst0 + nt_sub * ntStride + (size_t)chunk * 16) =
            *(const float4*)(smem + (size_t)c * 16);
    }
}

// ---------------- fused: router (NO atomics, first) + repack w1 ----------------

__global__ __launch_bounds__(256) void pre_kernel(
    const float* __restrict__ w1, char* __restrict__ w1blk,
    const float* __restrict__ x, const float* __restrict__ rw,
    const float* __restrict__ rb, unsigned short* __restrict__ xb,
    int* __restrict__ top_i, float* __restrict__ top_w) {
    __shared__ __align__(16) char smem[32768];
    const int bid = blockIdx.x;
    if (bid >= RT_BLKS) {
        // repack w1: rbid = ((e*16 + ks)*16 + nc)
        int rbid = bid - RT_BLKS;
        int nc = rbid & 15, ks = (rbid >> 4) & 15, e = rbid >> 8;
        const float* src = w1 + ((size_t)e * DIM + ks * 64) * HID + nc * 256;
        char* dst0 = w1blk + (((size_t)e * 32 + nc * 2) * 16 + ks) * 16384;
        repack_slab(src, HID, dst0, (size_t)16 * 16384, smem);
        return;
    }
    // router: one wave per token (fused x->bf16 conversion); atomic-free
    int t = bid * 4 + (threadIdx.x >> 6);
    int lane = threadIdx.x & 63;
    const float4* xr = (const float4*)(x + (size_t)t * DIM);
    float acc[NEXP];
#pragma unroll
    for (int e = 0; e < NEXP; ++e) acc[e] = 0.f;
#pragma unroll
    for (int i = 0; i < 4; ++i) {
        int vidx = lane + i * 64;
        float4 v = xr[vidx];
        ushort4 o;
        o.x = f2bf(v.x); o.y = f2bf(v.y); o.z = f2bf(v.z); o.w = f2bf(v.w);
        ((ushort4*)xb)[(size_t)t * 256 + vidx] = o;
        const float4* wr = (const float4*)(rw + (size_t)vidx * 4 * NEXP);
        float xs[4] = {v.x, v.y, v.z, v.w};
#pragma unroll
        for (int j = 0; j < 4; ++j) {
            float4 wlo = wr[j * 2 + 0], whi = wr[j * 2 + 1];
            acc[0] += xs[j] * wlo.x; acc[1] += xs[j] * wlo.y;
            acc[2] += xs[j] * wlo.z; acc[3] += xs[j] * wlo.w;
            acc[4] += xs[j] * whi.x; acc[5] += xs[j] * whi.y;
            acc[6] += xs[j] * whi.z; acc[7] += xs[j] * whi.w;
        }
    }
#pragma unroll
    for (int e = 0; e < NEXP; ++e) {
#pragma unroll
        for (int off = 32; off; off >>= 1) acc[e] += __shfl_xor(acc[e], off);
    }
    if (lane == 0) {
        float l[NEXP];
#pragma unroll
        for (int e = 0; e < NEXP; ++e) l[e] = acc[e] + rb[e];
        float best = -1e30f; int bi = 0;
#pragma unroll
        for (int e = 0; e < NEXP; ++e) if (l[e] > best) { best = l[e]; bi = e; }
        float best2 = -1e30f; int bi2 = 0;
#pragma unroll
        for (int e = 0; e < NEXP; ++e) { if (e == bi) continue; if (l[e] > best2) { best2 = l[e]; bi2 = e; } }
        float w0 = 1.f / (1.f + expf(best2 - best));
        top_i[t * 2] = bi;  top_i[t * 2 + 1] = bi2;
        top_w[t * 2] = w0;  top_w[t * 2 + 1] = 1.f - w0;
    }
}

// ---------------- plan: histogram + scan + slot assignment, ONE block, LDS atomics --------

__global__ __launch_bounds__(1024) void plan_kernel(
    const int* __restrict__ top_i, const float* __restrict__ top_w,
    int* __restrict__ counts, int* __restrict__ offsets, int* __restrict__ tile_start,
    int* __restrict__ row_token, float* __restrict__ row_w, int* __restrict__ slot_of) {
    __shared__ int hist[NEXP];
    __shared__ int offs[NEXP];
    __shared__ int curs[NEXP];
    const int tid = threadIdx.x;
    if (tid < NEXP) hist[tid] = 0;
    __syncthreads();
    int my_e[NSLOT / 1024];
#pragma unroll
    for (int c = 0; c < NSLOT / 1024; ++c) {
        int i = c * 1024 + tid;
        my_e[c] = top_i[i];
        atomicAdd(&hist[my_e[c]], 1);
    }
    __syncthreads();
    if (tid == 0) {
        int o = 0, t = 0;
#pragma unroll
        for (int e = 0; e < NEXP; ++e) {
            offs[e] = o; curs[e] = 0;
            counts[e] = hist[e];
            offsets[e] = o;
            tile_start[e] = t;
            t += (hist[e] + 127) >> 7;
            o += hist[e];
        }
        tile_start[NEXP] = t;
    }
    __syncthreads();
#pragma unroll
    for (int c = 0; c < NSLOT / 1024; ++c) {
        int i = c * 1024 + tid;
        int e = my_e[c];
        int s = atomicAdd(&curs[e], 1);
        int g = offs[e] + s;
        row_token[g] = i >> 1;
        row_w[g] = top_w[i];
        slot_of[i] = g;
    }
}

// ---------------- fused: GEMM1 (blocked-tile B) + repack w2 ----------------

__global__ __launch_bounds__(256, 4) void g1_kernel(
    const unsigned short* __restrict__ xb,    // [T][DIM] bf16
    const char* __restrict__ w1blk,           // blocked tiles
    const float* __restrict__ b1,             // [E][HID]
    const int* __restrict__ row_token, const int* __restrict__ offsets,
    const int* __restrict__ counts, const int* __restrict__ ts,
    unsigned short* __restrict__ h_ws,        // [NSLOT][HID] bf16
    const float* __restrict__ w2, char* __restrict__ w2blk) {
    __shared__ __align__(16) char smem[32768];
    const int bid = blockIdx.x;
    if (bid >= GRID1) {
        // repack w2: r = ((e*64 + ks)*4 + nc)
        int r = bid - GRID1;
        int nc = r & 3, ks = (r >> 2) & 63, e = r >> 8;
        const float* src = w2 + ((size_t)e * HID + ks * 64) * DIM + nc * 256;
        char* dst0 = w2blk + (((size_t)e * 8 + nc * 2) * 64 + ks) * 16384;
        repack_slab(src, DIM, dst0, (size_t)64 * 16384, smem);
        return;
    }
    const int xcd = bid & 7, s = bid >> 3;
    if (s >= 4 * ts[NEXP]) return;
    int e = 0;
#pragma unroll
    for (int k = 1; k < NEXP; ++k) if (s >= 4 * ts[k]) e = k;
    const int ntile = ts[e + 1] - ts[e];
    const int local = s - 4 * ts[e];
    const int q = local / ntile;              // 0..3
    const int mt = local - q * ntile;
    const int nt = q * 8 + xcd;               // 0..31
    const int cnt = counts[e];
    const int goff = offsets[e];

    unsigned short (*As)[64] = (unsigned short (*)[64])smem;            // 16 KB
    char* Bs = smem + 16384;                                            // 16 KB

    const int tid = threadIdx.x, wid = tid >> 6, lane = tid & 63;
    const int wm = wid >> 1, wn = wid & 1;

    f32x4 acc[4][4];
#pragma unroll
    for (int i = 0; i < 4; ++i)
#pragma unroll
        for (int j = 0; j < 4; ++j) acc[i][j] = (f32x4){0.f, 0.f, 0.f, 0.f};

    const unsigned short* srcA[4];
#pragma unroll
    for (int it = 0; it < 4; ++it) {
        int idx = it * 256 + tid;
        int r = idx >> 3, kg = idx & 7;
        int sk = kg ^ (r & 7);                 // swizzled source chunk
        int rr = mt * 128 + r;
        int tok = row_token[goff + (rr < cnt ? rr : 0)];
        srcA[it] = xb + (size_t)tok * DIM + sk * 8;
    }
    const char* btile = w1blk + (((size_t)e * 32 + nt) * 16) * 16384;

    for (int t = 0; t < 16; ++t) {
        const int k0 = t * 64;
        const char* bsrc = btile + (size_t)t * 16384;
#pragma unroll
        for (int it = 0; it < 4; ++it) {
            __builtin_amdgcn_global_load_lds(AS1(srcA[it] + k0),
                AS3((char*)As + (it * 4 + wid) * 1024), 16, 0, 0);
            __builtin_amdgcn_global_load_lds(AS1(bsrc + (size_t)(it * 256 + tid) * 16),
                AS3(Bs + (it * 4 + wid) * 1024), 16, 0, 0);
        }
        __syncthreads();                       // drains vmcnt: tile ready
#pragma unroll
        for (int kk = 0; kk < 2; ++kk) {
            bf16x8 a[4], b[4];
            int ch = (kk * 4 + (lane >> 4)) ^ (lane & 7);
#pragma unroll
            for (int i = 0; i < 4; ++i) {
                int row = wm * 64 + i * 16 + (lane & 15);
                a[i] = *(const bf16x8*)((const char*)As + row * 128 + ch * 16);
            }
#pragma unroll
            for (int i = 0; i < 4; ++i) {
                int row = wn * 64 + i * 16 + (lane & 15);
                b[i] = *(const bf16x8*)(Bs + row * 128 + ch * 16);
            }
#pragma unroll
            for (int i = 0; i < 4; ++i)
#pragma unroll
                for (int j = 0; j < 4; ++j)
                    acc[i][j] = mfma16(a[i], b[j], acc[i][j]);
        }
        __syncthreads();
    }

    if (mt * 128 + 128 <= cnt) {               // fast path: full tile
#pragma unroll
        for (int j = 0; j < 4; ++j) {
            int n = nt * 128 + wn * 64 + j * 16 + (lane & 15);
            float bias = b1[e * HID + n];
#pragma unroll
            for (int i = 0; i < 4; ++i) {
#pragma unroll
                for (int q2 = 0; q2 < 4; ++q2) {
                    int rr = mt * 128 + wm * 64 + i * 16 + (lane >> 4) * 4 + q2;
                    float v = fmaxf(acc[i][j][q2] + bias, 0.f);
                    h_ws[(size_t)(goff + rr) * HID + n] = f2bf(v);
                }
            }
        }
    } else {
#pragma unroll
        for (int j = 0; j < 4; ++j) {
            int n = nt * 128 + wn * 64 + j * 16 + (lane & 15);
            float bias = b1[e * HID + n];
#pragma unroll
            for (int i = 0; i < 4; ++i) {
#pragma unroll
                for (int q2 = 0; q2 < 4; ++q2) {
                    int rr = mt * 128 + wm * 64 + i * 16 + (lane >> 4) * 4 + q2;
                    if (rr < cnt) {
                        float v = fmaxf(acc[i][j][q2] + bias, 0.f);
                        h_ws[(size_t)(goff + rr) * HID + n] = f2bf(v);
                    }
                }
            }
        }
    }
}

// GEMM2 (split-K, blocked-tile B): y_part[ks][slot][n] = sum_{k in slice} h[slot][k]*w2[k][n]
__global__ __launch_bounds__(256, 4) void gemm2_kernel(
    const unsigned short* __restrict__ h_ws,  // [NSLOT][HID] bf16
    const char* __restrict__ w2blk,           // blocked tiles
    const int* __restrict__ offsets, const int* __restrict__ counts,
    const int* __restrict__ ts,
    float* __restrict__ y_part) {             // [KSPLIT][NSLOT][DIM] f32
    const int bid = blockIdx.x;
    const int xcd = bid & 7, s = bid >> 3;
    if (s >= 2 * ts[NEXP]) return;
    int e = 0;
#pragma unroll
    for (int k = 1; k < NEXP; ++k) if (s >= 2 * ts[k]) e = k;
    const int ntile = ts[e + 1] - ts[e];
    const int local = s - 2 * ts[e];
    const int ks = local / ntile;             // 0..1
    const int mt = local - ks * ntile;
    const int nt = xcd;                       // 0..7
    const int cnt = counts[e];
    const int goff = offsets[e];

    __shared__ __align__(16) char smem[32768];
    unsigned short (*As)[64] = (unsigned short (*)[64])smem;
    char* Bs = smem + 16384;

    const int tid = threadIdx.x, wid = tid >> 6, lane = tid & 63;
    const int wm = wid >> 1, wn = wid & 1;

    f32x4 acc[4][4];
#pragma unroll
    for (int i = 0; i < 4; ++i)
#pragma unroll
        for (int j = 0; j < 4; ++j) acc[i][j] = (f32x4){0.f, 0.f, 0.f, 0.f};

    const unsigned short* srcA[4];
#pragma unroll
    for (int it = 0; it < 4; ++it) {
        int idx = it * 256 + tid;
        int r = idx >> 3, kg = idx & 7;
        int sk = kg ^ (r & 7);
        int rr = mt * 128 + r;
        int g = goff + (rr < cnt ? rr : 0);
        srcA[it] = h_ws + (size_t)g * HID + sk * 8;
    }
    const char* btile = w2blk + (((size_t)e * 8 + nt) * 64 + ks * 32) * 16384;

    const int kbase = ks * KS_LEN;
    for (int t = 0; t < KS_LEN / 64; ++t) {
        const int k0 = kbase + t * 64;
        const char* bsrc = btile + (size_t)t * 16384;
#pragma unroll
        for (int it = 0; it < 4; ++it) {
            __builtin_amdgcn_global_load_lds(AS1(srcA[it] + k0),
                AS3((char*)As + (it * 4 + wid) * 1024), 16, 0, 0);
            __builtin_amdgcn_global_load_lds(AS1(bsrc + (size_t)(it * 256 + tid) * 16),
                AS3(Bs + (it * 4 + wid) * 1024), 16, 0, 0);
        }
        __syncthreads();
#pragma unroll
        for (int kk = 0; kk < 2; ++kk) {
            bf16x8 a[4], b[4];
            int ch = (kk * 4 + (lane >> 4)) ^ (lane & 7);
#pragma unroll
            for (int i = 0; i < 4; ++i) {
                int row = wm * 64 + i * 16 + (lane & 15);
                a[i] = *(const bf16x8*)((const char*)As + row * 128 + ch * 16);
            }
#pragma unroll
            for (int i = 0; i < 4; ++i) {
                int row = wn * 64 + i * 16 + (lane & 15);
                b[i] = *(const bf16x8*)(Bs + row * 128 + ch * 16);
            }
#pragma unroll
            for (int i = 0; i < 4; ++i)
#pragma unroll
                for (int j = 0; j < 4; ++j)
                    acc[i][j] = mfma16(a[i], b[j], acc[i][j]);
        }
        __syncthreads();
    }

    if (mt * 128 + 128 <= cnt) {
#pragma unroll
        for (int j = 0; j < 4; ++j) {
            int n = nt * 128 + wn * 64 + j * 16 + (lane & 15);
#pragma unroll
            for (int i = 0; i < 4; ++i) {
#pragma unroll
                for (int q2 = 0; q2 < 4; ++q2) {
                    int rr = mt * 128 + wm * 64 + i * 16 + (lane >> 4) * 4 + q2;
                    y_part[((size_t)ks * NSLOT + goff + rr) * DIM + n] = acc[i][j][q2];
                }
            }
        }
    } else {
#pragma unroll
        for (int j = 0; j < 4; ++j) {
            int n = nt * 128 + wn * 64 + j * 16 + (lane & 15);
#pragma unroll
            for (int i = 0; i < 4; ++i) {
#pragma unroll
                for (int q2 = 0; q2 < 4; ++q2) {
                    int rr = mt * 128 + wm * 64 + i * 16 + (lane >> 4) * 4 + q2;
                    if (rr < cnt) {
                        y_part[((size_t)ks * NSLOT + goff + rr) * DIM + n] = acc[i][j][q2];
                    }
                }
            }
        }
    }
}

// out[t][d] = w0*(p0[s0]+p1[s0]+b2[e0]) + w1*(p0[s1]+p1[s1]+b2[e1])
__global__ __launch_bounds__(256) void combine_kernel(
    const float* __restrict__ y_part, const int* __restrict__ slot_of,
    const int* __restrict__ top_i, const float* __restrict__ top_w,
    const float* __restrict__ b2, float* __restrict__ out) {
    int i = blockIdx.x * 256 + threadIdx.x;
    int t = i >> 8, c = i & 255;
    int s0 = slot_of[t * 2], s1 = slot_of[t * 2 + 1];
    int e0 = top_i[t * 2],  e1 = top_i[t * 2 + 1];
    float w0 = top_w[t * 2], w1 = top_w[t * 2 + 1];
    const float4* P = (const float4*)y_part;
    float4 p00 = P[(size_t)s0 * 256 + c];
    float4 p01 = P[((size_t)NSLOT + s0) * 256 + c];
    float4 p10 = P[(size_t)s1 * 256 + c];
    float4 p11 = P[((size_t)NSLOT + s1) * 256 + c];
    float4 b0 = ((const float4*)b2)[e0 * 256 + c];
    float4 b1 = ((const float4*)b2)[e1 * 256 + c];
    float4 o;
    o.x = w0 * (p00.x + p01.x + b0.x) + w1 * (p10.x + p11.x + b1.x);
    o.y = w0 * (p00.y + p01.y + b0.y) + w1 * (p10.y + p11.y + b1.y);
    o.z = w0 * (p00.z + p01.z + b0.z) + w1 * (p10.z + p11.z + b1.z);
    o.w = w0 * (p00.w + p01.w + b0.w) + w1 * (p10.w + p11.w + b1.w);
    ((float4*)out)[i] = o;
}

// ---------------- launch ----------------

extern "C" void kernel_launch(void* const* d_in, const int* in_sizes, int n_in,
                              void* d_out, int out_size, void* d_ws, size_t ws_size,
                              hipStream_t stream) {
    const float* x   = (const float*)d_in[0];
    const float* rw  = (const float*)d_in[1];
    const float* rb  = (const float*)d_in[2];
    const float* w1  = (const float*)d_in[3];
    const float* b1  = (const float*)d_in[4];
    const float* w2  = (const float*)d_in[5];
    const float* b2  = (const float*)d_in[6];
    float* out = (float*)d_out;

    char* ws = (char*)d_ws;
    size_t off = 0;
    auto alloc = [&](size_t bytes) { size_t r = off; off = (off + bytes + 255) & ~(size_t)255; return r; };
    unsigned short* xb   = (unsigned short*)(ws + alloc((size_t)T_TOK * DIM * 2));   // 8 MB
    char* w1blk          = ws + alloc((size_t)NEXP * DIM * HID * 2);                  // 64 MB
    char* w2blk          = ws + alloc((size_t)NEXP * HID * DIM * 2);                  // 64 MB
    unsigned short* h_ws = (unsigned short*)(ws + alloc((size_t)NSLOT * HID * 2));   // 64 MB
    int*   top_i         = (int*)(ws + alloc((size_t)NSLOT * 4));
    float* top_w         = (float*)(ws + alloc((size_t)NSLOT * 4));
    int*   slot_of       = (int*)(ws + alloc((size_t)NSLOT * 4));
    int*   row_token     = (int*)(ws + alloc((size_t)NSLOT * 4));
    float* row_w         = (float*)(ws + alloc((size_t)NSLOT * 4));
    char*  ctrl          = ws + alloc(256);
    int* counts     = (int*)(ctrl);
    int* offsets    = (int*)(ctrl + 64);
    int* tile_start = (int*)(ctrl + 128);
    // y_part (64 MB) aliases w1blk: dead once g1 completes; gemm2/combine follow on-stream.
    float* y_part = (float*)w1blk;

    // fused: router (atomic-free, first) + repack w1 (blocked tiles, conflict-free fill)
    pre_kernel<<<RT_BLKS + RP1_BLKS, 256, 0, stream>>>(w1, w1blk, x, rw, rb, xb,
                                                       top_i, top_w);
    // single-block plan: histogram + offsets + slot assignment via LDS atomics
    plan_kernel<<<1, 1024, 0, stream>>>(top_i, top_w, counts, offsets, tile_start,
                                        row_token, row_w, slot_of);

    // fused: gemm1 (blocked B) + repack w2 (consumed by gemm2, next launch)
    g1_kernel<<<GRID1 + RP2_BLKS, 256, 0, stream>>>(xb, w1blk, b1, row_token, offsets,
                                                    counts, tile_start, h_ws, w2, w2blk);
    gemm2_kernel<<<GRID2, 256, 0, stream>>>(h_ws, w2blk, offsets, counts, tile_start, y_part);

    combine_kernel<<<T_TOK * 256 / 256, 256, 0, stream>>>(y_part, slot_of, top_i, top_w, b2, out);
}

// Round 20
// 287.724 us; speedup vs baseline: 1.1430x; 1.0295x over previous
//
#include <hip/hip_runtime.h>
#include <hip/hip_bf16.h>
#include <stdint.h>

#define T_TOK 4096
#define DIM   1024
#define HID   4096
#define NEXP  8
#define NSLOT (T_TOK * 2)
#define KSPLIT 2
#define KS_LEN (HID / KSPLIT)
#define MAXMT 72                 // max sum of ceil(cnt_e/128)
#define GRID1 (8 * 4 * MAXMT)    // 2304 gemm1 job slots
#define GRID2 (8 * 2 * MAXMT)    // 1152 gemm2 job slots
#define RT_BLKS 1024             // router blocks (first, so they start immediately)
#define RP1_BLKS 2048            // w1 repack: 8 e x 16 ks x 16 nc
#define RP2_BLKS 2048            // w2 repack: 8 e x 64 ks x 4 nc

typedef __attribute__((ext_vector_type(8))) short bf16x8;
typedef __attribute__((ext_vector_type(4))) float f32x4;

#define AS1(p) ((const __attribute__((address_space(1))) void*)(p))
#define AS3(p) ((__attribute__((address_space(3))) void*)(p))

static __device__ __forceinline__ unsigned short f2bf(float f) {
    unsigned int u = __float_as_uint(f);
    unsigned int r = (u + 0x7fffu + ((u >> 16) & 1u)) >> 16;
    return (unsigned short)r;
}

static __device__ __forceinline__ float bf2f(short v) {
    return __uint_as_float((unsigned int)(unsigned short)v << 16);
}

static __device__ __forceinline__ f32x4 mfma16(bf16x8 a, bf16x8 b, f32x4 c) {
    return __builtin_amdgcn_mfma_f32_16x16x32_bf16(a, b, c, 0, 0, 0);
}

// ---------------- repack one [64k x 256n] slab into 2 pre-swizzled 16KB GEMM tiles --------
// Fill: lane owns chunk (gc, nl=q*64+lane); 8 scalar fp32 loads (each instr = 256B
// coalesced segment), pack bf16x8, ONE ds_write_b128 (conflict-free: lanes have
// consecutive r -> chunk cols cover all 8 banks-quads). Drain: sequential 16KB write-out.
// Tile byte r*128 + (gc^(r&7))*16 + kp*2 holds element (k = gc*8+kp, n-row r).
static __device__ __forceinline__ void repack_slab(
    const float* __restrict__ src, int N, char* __restrict__ dst0,
    size_t ntStride, char* smem) {
    const int lane = threadIdx.x & 63;
    const int w = threadIdx.x >> 6;
#pragma unroll
    for (int h = 0; h < 2; ++h) {
        const int gc = w + h * 4;
#pragma unroll
        for (int q = 0; q < 4; ++q) {
            const int nl = q * 64 + lane;
            const int nt_sub = nl >> 7, r = nl & 127;
            const float* p = src + (size_t)(gc * 8) * N + nl;
            bf16x8 v = {(short)f2bf(p[0]),
                        (short)f2bf(p[(size_t)1 * N]),
                        (short)f2bf(p[(size_t)2 * N]),
                        (short)f2bf(p[(size_t)3 * N]),
                        (short)f2bf(p[(size_t)4 * N]),
                        (short)f2bf(p[(size_t)5 * N]),
                        (short)f2bf(p[(size_t)6 * N]),
                        (short)f2bf(p[(size_t)7 * N])};
            *(bf16x8*)(smem + nt_sub * 16384 + r * 128 + ((gc ^ (r & 7)) << 4)) = v;
        }
    }
    __syncthreads();
    const int tid = threadIdx.x;
#pragma unroll
    for (int i = 0; i < 8; ++i) {
        int c = i * 256 + tid;                 // 2048 x 16B
        int nt_sub = c >> 10, chunk = c & 1023;
        *(float4*)(dst0 + nt_sub * ntStride + (size_t)chunk * 16) =
            *(const float4*)(smem + (size_t)c * 16);
    }
}

// ---------------- fused: router (NO atomics, first) + repack w1 ----------------

__global__ __launch_bounds__(256) void pre_kernel(
    const float* __restrict__ w1, char* __restrict__ w1blk,
    const float* __restrict__ x, const float* __restrict__ rw,
    const float* __restrict__ rb, unsigned short* __restrict__ xb,
    int* __restrict__ top_i, float* __restrict__ top_w) {
    __shared__ __align__(16) char smem[32768];
    const int bid = blockIdx.x;
    if (bid >= RT_BLKS) {
        // repack w1: rbid = ((e*16 + ks)*16 + nc)
        int rbid = bid - RT_BLKS;
        int nc = rbid & 15, ks = (rbid >> 4) & 15, e = rbid >> 8;
        const float* src = w1 + ((size_t)e * DIM + ks * 64) * HID + nc * 256;
        char* dst0 = w1blk + (((size_t)e * 32 + nc * 2) * 16 + ks) * 16384;
        repack_slab(src, HID, dst0, (size_t)16 * 16384, smem);
        return;
    }
    // router: one wave per token (fused x->bf16 conversion); atomic-free
    int t = bid * 4 + (threadIdx.x >> 6);
    int lane = threadIdx.x & 63;
    const float4* xr = (const float4*)(x + (size_t)t * DIM);
    float acc[NEXP];
#pragma unroll
    for (int e = 0; e < NEXP; ++e) acc[e] = 0.f;
#pragma unroll
    for (int i = 0; i < 4; ++i) {
        int vidx = lane + i * 64;
        float4 v = xr[vidx];
        ushort4 o;
        o.x = f2bf(v.x); o.y = f2bf(v.y); o.z = f2bf(v.z); o.w = f2bf(v.w);
        ((ushort4*)xb)[(size_t)t * 256 + vidx] = o;
        const float4* wr = (const float4*)(rw + (size_t)vidx * 4 * NEXP);
        float xs[4] = {v.x, v.y, v.z, v.w};
#pragma unroll
        for (int j = 0; j < 4; ++j) {
            float4 wlo = wr[j * 2 + 0], whi = wr[j * 2 + 1];
            acc[0] += xs[j] * wlo.x; acc[1] += xs[j] * wlo.y;
            acc[2] += xs[j] * wlo.z; acc[3] += xs[j] * wlo.w;
            acc[4] += xs[j] * whi.x; acc[5] += xs[j] * whi.y;
            acc[6] += xs[j] * whi.z; acc[7] += xs[j] * whi.w;
        }
    }
#pragma unroll
    for (int e = 0; e < NEXP; ++e) {
#pragma unroll
        for (int off = 32; off; off >>= 1) acc[e] += __shfl_xor(acc[e], off);
    }
    if (lane == 0) {
        float l[NEXP];
#pragma unroll
        for (int e = 0; e < NEXP; ++e) l[e] = acc[e] + rb[e];
        float best = -1e30f; int bi = 0;
#pragma unroll
        for (int e = 0; e < NEXP; ++e) if (l[e] > best) { best = l[e]; bi = e; }
        float best2 = -1e30f; int bi2 = 0;
#pragma unroll
        for (int e = 0; e < NEXP; ++e) { if (e == bi) continue; if (l[e] > best2) { best2 = l[e]; bi2 = e; } }
        float w0 = 1.f / (1.f + expf(best2 - best));
        top_i[t * 2] = bi;  top_i[t * 2 + 1] = bi2;
        top_w[t * 2] = w0;  top_w[t * 2 + 1] = 1.f - w0;
    }
}

// ---------------- plan: histogram + scan + slot assignment, ONE block, LDS atomics --------

__global__ __launch_bounds__(1024) void plan_kernel(
    const int* __restrict__ top_i, const float* __restrict__ top_w,
    int* __restrict__ counts, int* __restrict__ offsets, int* __restrict__ tile_start,
    int* __restrict__ row_token, float* __restrict__ row_w, int* __restrict__ slot_of) {
    __shared__ int hist[NEXP];
    __shared__ int offs[NEXP];
    __shared__ int curs[NEXP];
    const int tid = threadIdx.x;
    if (tid < NEXP) hist[tid] = 0;
    __syncthreads();
    int my_e[NSLOT / 1024];
#pragma unroll
    for (int c = 0; c < NSLOT / 1024; ++c) {
        int i = c * 1024 + tid;
        my_e[c] = top_i[i];
        atomicAdd(&hist[my_e[c]], 1);
    }
    __syncthreads();
    if (tid == 0) {
        int o = 0, t = 0;
#pragma unroll
        for (int e = 0; e < NEXP; ++e) {
            offs[e] = o; curs[e] = 0;
            counts[e] = hist[e];
            offsets[e] = o;
            tile_start[e] = t;
            t += (hist[e] + 127) >> 7;
            o += hist[e];
        }
        tile_start[NEXP] = t;
    }
    __syncthreads();
#pragma unroll
    for (int c = 0; c < NSLOT / 1024; ++c) {
        int i = c * 1024 + tid;
        int e = my_e[c];
        int s = atomicAdd(&curs[e], 1);
        int g = offs[e] + s;
        row_token[g] = i >> 1;
        row_w[g] = top_w[i];
        slot_of[i] = g;
    }
}

// ---------------- fused: GEMM1 (blocked-tile B) + repack w2 ----------------

__global__ __launch_bounds__(256, 4) void g1_kernel(
    const unsigned short* __restrict__ xb,    // [T][DIM] bf16
    const char* __restrict__ w1blk,           // blocked tiles
    const float* __restrict__ b1,             // [E][HID]
    const int* __restrict__ row_token, const int* __restrict__ offsets,
    const int* __restrict__ counts, const int* __restrict__ ts,
    unsigned short* __restrict__ h_ws,        // [NSLOT][HID] bf16
    const float* __restrict__ w2, char* __restrict__ w2blk) {
    __shared__ __align__(16) char smem[32768];
    const int bid = blockIdx.x;
    if (bid >= GRID1) {
        // repack w2: r = ((e*64 + ks)*4 + nc)
        int r = bid - GRID1;
        int nc = r & 3, ks = (r >> 2) & 63, e = r >> 8;
        const float* src = w2 + ((size_t)e * HID + ks * 64) * DIM + nc * 256;
        char* dst0 = w2blk + (((size_t)e * 8 + nc * 2) * 64 + ks) * 16384;
        repack_slab(src, DIM, dst0, (size_t)64 * 16384, smem);
        return;
    }
    const int xcd = bid & 7, s = bid >> 3;
    if (s >= 4 * ts[NEXP]) return;
    int e = 0;
#pragma unroll
    for (int k = 1; k < NEXP; ++k) if (s >= 4 * ts[k]) e = k;
    const int ntile = ts[e + 1] - ts[e];
    const int local = s - 4 * ts[e];
    const int q = local / ntile;              // 0..3
    const int mt = local - q * ntile;
    const int nt = q * 8 + xcd;               // 0..31
    const int cnt = counts[e];
    const int goff = offsets[e];

    unsigned short (*As)[64] = (unsigned short (*)[64])smem;            // 16 KB
    char* Bs = smem + 16384;                                            // 16 KB

    const int tid = threadIdx.x, wid = tid >> 6, lane = tid & 63;
    const int wm = wid >> 1, wn = wid & 1;

    f32x4 acc[4][4];
#pragma unroll
    for (int i = 0; i < 4; ++i)
#pragma unroll
        for (int j = 0; j < 4; ++j) acc[i][j] = (f32x4){0.f, 0.f, 0.f, 0.f};

    const unsigned short* srcA[4];
#pragma unroll
    for (int it = 0; it < 4; ++it) {
        int idx = it * 256 + tid;
        int r = idx >> 3, kg = idx & 7;
        int sk = kg ^ (r & 7);                 // swizzled source chunk
        int rr = mt * 128 + r;
        int tok = row_token[goff + (rr < cnt ? rr : 0)];
        srcA[it] = xb + (size_t)tok * DIM + sk * 8;
    }
    const char* btile = w1blk + (((size_t)e * 32 + nt) * 16) * 16384;

    for (int t = 0; t < 16; ++t) {
        const int k0 = t * 64;
        const char* bsrc = btile + (size_t)t * 16384;
#pragma unroll
        for (int it = 0; it < 4; ++it) {
            __builtin_amdgcn_global_load_lds(AS1(srcA[it] + k0),
                AS3((char*)As + (it * 4 + wid) * 1024), 16, 0, 0);
            __builtin_amdgcn_global_load_lds(AS1(bsrc + (size_t)(it * 256 + tid) * 16),
                AS3(Bs + (it * 4 + wid) * 1024), 16, 0, 0);
        }
        __syncthreads();                       // drains vmcnt: tile ready
#pragma unroll
        for (int kk = 0; kk < 2; ++kk) {
            bf16x8 a[4], b[4];
            int ch = (kk * 4 + (lane >> 4)) ^ (lane & 7);
#pragma unroll
            for (int i = 0; i < 4; ++i) {
                int row = wm * 64 + i * 16 + (lane & 15);
                a[i] = *(const bf16x8*)((const char*)As + row * 128 + ch * 16);
            }
#pragma unroll
            for (int i = 0; i < 4; ++i) {
                int row = wn * 64 + i * 16 + (lane & 15);
                b[i] = *(const bf16x8*)(Bs + row * 128 + ch * 16);
            }
#pragma unroll
            for (int i = 0; i < 4; ++i)
#pragma unroll
                for (int j = 0; j < 4; ++j)
                    acc[i][j] = mfma16(a[i], b[j], acc[i][j]);
        }
        __syncthreads();
    }

    if (mt * 128 + 128 <= cnt) {               // fast path: full tile
#pragma unroll
        for (int j = 0; j < 4; ++j) {
            int n = nt * 128 + wn * 64 + j * 16 + (lane & 15);
            float bias = b1[e * HID + n];
#pragma unroll
            for (int i = 0; i < 4; ++i) {
#pragma unroll
                for (int q2 = 0; q2 < 4; ++q2) {
                    int rr = mt * 128 + wm * 64 + i * 16 + (lane >> 4) * 4 + q2;
                    float v = fmaxf(acc[i][j][q2] + bias, 0.f);
                    h_ws[(size_t)(goff + rr) * HID + n] = f2bf(v);
                }
            }
        }
    } else {
#pragma unroll
        for (int j = 0; j < 4; ++j) {
            int n = nt * 128 + wn * 64 + j * 16 + (lane & 15);
            float bias = b1[e * HID + n];
#pragma unroll
            for (int i = 0; i < 4; ++i) {
#pragma unroll
                for (int q2 = 0; q2 < 4; ++q2) {
                    int rr = mt * 128 + wm * 64 + i * 16 + (lane >> 4) * 4 + q2;
                    if (rr < cnt) {
                        float v = fmaxf(acc[i][j][q2] + bias, 0.f);
                        h_ws[(size_t)(goff + rr) * HID + n] = f2bf(v);
                    }
                }
            }
        }
    }
}

// GEMM2 (split-K, blocked-tile B): y_part[ks][slot][n] (bf16) = sum_{k} h[slot][k]*w2[k][n]
__global__ __launch_bounds__(256, 4) void gemm2_kernel(
    const unsigned short* __restrict__ h_ws,  // [NSLOT][HID] bf16
    const char* __restrict__ w2blk,           // blocked tiles
    const int* __restrict__ offsets, const int* __restrict__ counts,
    const int* __restrict__ ts,
    unsigned short* __restrict__ y_part) {    // [KSPLIT][NSLOT][DIM] bf16
    const int bid = blockIdx.x;
    const int xcd = bid & 7, s = bid >> 3;
    if (s >= 2 * ts[NEXP]) return;
    int e = 0;
#pragma unroll
    for (int k = 1; k < NEXP; ++k) if (s >= 2 * ts[k]) e = k;
    const int ntile = ts[e + 1] - ts[e];
    const int local = s - 2 * ts[e];
    const int ks = local / ntile;             // 0..1
    const int mt = local - ks * ntile;
    const int nt = xcd;                       // 0..7
    const int cnt = counts[e];
    const int goff = offsets[e];

    __shared__ __align__(16) char smem[32768];
    unsigned short (*As)[64] = (unsigned short (*)[64])smem;
    char* Bs = smem + 16384;

    const int tid = threadIdx.x, wid = tid >> 6, lane = tid & 63;
    const int wm = wid >> 1, wn = wid & 1;

    f32x4 acc[4][4];
#pragma unroll
    for (int i = 0; i < 4; ++i)
#pragma unroll
        for (int j = 0; j < 4; ++j) acc[i][j] = (f32x4){0.f, 0.f, 0.f, 0.f};

    const unsigned short* srcA[4];
#pragma unroll
    for (int it = 0; it < 4; ++it) {
        int idx = it * 256 + tid;
        int r = idx >> 3, kg = idx & 7;
        int sk = kg ^ (r & 7);
        int rr = mt * 128 + r;
        int g = goff + (rr < cnt ? rr : 0);
        srcA[it] = h_ws + (size_t)g * HID + sk * 8;
    }
    const char* btile = w2blk + (((size_t)e * 8 + nt) * 64 + ks * 32) * 16384;

    const int kbase = ks * KS_LEN;
    for (int t = 0; t < KS_LEN / 64; ++t) {
        const int k0 = kbase + t * 64;
        const char* bsrc = btile + (size_t)t * 16384;
#pragma unroll
        for (int it = 0; it < 4; ++it) {
            __builtin_amdgcn_global_load_lds(AS1(srcA[it] + k0),
                AS3((char*)As + (it * 4 + wid) * 1024), 16, 0, 0);
            __builtin_amdgcn_global_load_lds(AS1(bsrc + (size_t)(it * 256 + tid) * 16),
                AS3(Bs + (it * 4 + wid) * 1024), 16, 0, 0);
        }
        __syncthreads();
#pragma unroll
        for (int kk = 0; kk < 2; ++kk) {
            bf16x8 a[4], b[4];
            int ch = (kk * 4 + (lane >> 4)) ^ (lane & 7);
#pragma unroll
            for (int i = 0; i < 4; ++i) {
                int row = wm * 64 + i * 16 + (lane & 15);
                a[i] = *(const bf16x8*)((const char*)As + row * 128 + ch * 16);
            }
#pragma unroll
            for (int i = 0; i < 4; ++i) {
                int row = wn * 64 + i * 16 + (lane & 15);
                b[i] = *(const bf16x8*)(Bs + row * 128 + ch * 16);
            }
#pragma unroll
            for (int i = 0; i < 4; ++i)
#pragma unroll
                for (int j = 0; j < 4; ++j)
                    acc[i][j] = mfma16(a[i], b[j], acc[i][j]);
        }
        __syncthreads();
    }

    if (mt * 128 + 128 <= cnt) {
#pragma unroll
        for (int j = 0; j < 4; ++j) {
            int n = nt * 128 + wn * 64 + j * 16 + (lane & 15);
#pragma unroll
            for (int i = 0; i < 4; ++i) {
#pragma unroll
                for (int q2 = 0; q2 < 4; ++q2) {
                    int rr = mt * 128 + wm * 64 + i * 16 + (lane >> 4) * 4 + q2;
                    y_part[((size_t)ks * NSLOT + goff + rr) * DIM + n] = f2bf(acc[i][j][q2]);
                }
            }
        }
    } else {
#pragma unroll
        for (int j = 0; j < 4; ++j) {
            int n = nt * 128 + wn * 64 + j * 16 + (lane & 15);
#pragma unroll
            for (int i = 0; i < 4; ++i) {
#pragma unroll
                for (int q2 = 0; q2 < 4; ++q2) {
                    int rr = mt * 128 + wm * 64 + i * 16 + (lane >> 4) * 4 + q2;
                    if (rr < cnt) {
                        y_part[((size_t)ks * NSLOT + goff + rr) * DIM + n] = f2bf(acc[i][j][q2]);
                    }
                }
            }
        }
    }
}

// out[t][d0..d0+7] = w0*(p00+p01+b2[e0]) + w1*(p10+p11+b2[e1])   (bf16 partials)
__global__ __launch_bounds__(256) void combine_kernel(
    const unsigned short* __restrict__ y_part, const int* __restrict__ slot_of,
    const int* __restrict__ top_i, const float* __restrict__ top_w,
    const float* __restrict__ b2, float* __restrict__ out) {
    int i = blockIdx.x * 256 + threadIdx.x;    // T_TOK*128 threads; 8 outputs each
    int t = i >> 7, c = i & 127;
    int s0 = slot_of[t * 2], s1 = slot_of[t * 2 + 1];
    int e0 = top_i[t * 2],  e1 = top_i[t * 2 + 1];
    float w0 = top_w[t * 2], w1 = top_w[t * 2 + 1];
    const bf16x8* Y = (const bf16x8*)y_part;   // index = (ks*NSLOT + slot)*128 + c
    bf16x8 p00 = Y[(size_t)s0 * 128 + c];
    bf16x8 p01 = Y[((size_t)NSLOT + s0) * 128 + c];
    bf16x8 p10 = Y[(size_t)s1 * 128 + c];
    bf16x8 p11 = Y[((size_t)NSLOT + s1) * 128 + c];
    const float* b0p = b2 + e0 * DIM + c * 8;
    const float* b1p = b2 + e1 * DIM + c * 8;
    float res[8];
#pragma unroll
    for (int j = 0; j < 8; ++j) {
        float v0 = bf2f(p00[j]) + bf2f(p01[j]) + b0p[j];
        float v1 = bf2f(p10[j]) + bf2f(p11[j]) + b1p[j];
        res[j] = w0 * v0 + w1 * v1;
    }
    float4* op = (float4*)(out + (size_t)t * DIM + c * 8);
    op[0] = (float4){res[0], res[1], res[2], res[3]};
    op[1] = (float4){res[4], res[5], res[6], res[7]};
}

// ---------------- launch ----------------

extern "C" void kernel_launch(void* const* d_in, const int* in_sizes, int n_in,
                              void* d_out, int out_size, void* d_ws, size_t ws_size,
                              hipStream_t stream) {
    const float* x   = (const float*)d_in[0];
    const float* rw  = (const float*)d_in[1];
    const float* rb  = (const float*)d_in[2];
    const float* w1  = (const float*)d_in[3];
    const float* b1  = (const float*)d_in[4];
    const float* w2  = (const float*)d_in[5];
    const float* b2  = (const float*)d_in[6];
    float* out = (float*)d_out;

    char* ws = (char*)d_ws;
    size_t off = 0;
    auto alloc = [&](size_t bytes) { size_t r = off; off = (off + bytes + 255) & ~(size_t)255; return r; };
    unsigned short* xb   = (unsigned short*)(ws + alloc((size_t)T_TOK * DIM * 2));   // 8 MB
    char* w1blk          = ws + alloc((size_t)NEXP * DIM * HID * 2);                  // 64 MB
    char* w2blk          = ws + alloc((size_t)NEXP * HID * DIM * 2);                  // 64 MB
    unsigned short* h_ws = (unsigned short*)(ws + alloc((size_t)NSLOT * HID * 2));   // 64 MB
    int*   top_i         = (int*)(ws + alloc((size_t)NSLOT * 4));
    float* top_w         = (float*)(ws + alloc((size_t)NSLOT * 4));
    int*   slot_of       = (int*)(ws + alloc((size_t)NSLOT * 4));
    int*   row_token     = (int*)(ws + alloc((size_t)NSLOT * 4));
    float* row_w         = (float*)(ws + alloc((size_t)NSLOT * 4));
    char*  ctrl          = ws + alloc(256);
    int* counts     = (int*)(ctrl);
    int* offsets    = (int*)(ctrl + 64);
    int* tile_start = (int*)(ctrl + 128);
    // y_part (KSPLIT x NSLOT x DIM bf16 = 32 MB) aliases w1blk: dead once g1 completes.
    unsigned short* y_part = (unsigned short*)w1blk;

    // fused: router (atomic-free, first) + repack w1 (blocked tiles, conflict-free fill)
    pre_kernel<<<RT_BLKS + RP1_BLKS, 256, 0, stream>>>(w1, w1blk, x, rw, rb, xb,
                                                       top_i, top_w);
    // single-block plan: histogram + offsets + slot assignment via LDS atomics
    plan_kernel<<<1, 1024, 0, stream>>>(top_i, top_w, counts, offsets, tile_start,
                                        row_token, row_w, slot_of);

    // fused: gemm1 (blocked B) + repack w2 (consumed by gemm2, next launch)
    g1_kernel<<<GRID1 + RP2_BLKS, 256, 0, stream>>>(xb, w1blk, b1, row_token, offsets,
                                                    counts, tile_start, h_ws, w2, w2blk);
    gemm2_kernel<<<GRID2, 256, 0, stream>>>(h_ws, w2blk, offsets, counts, tile_start, y_part);

    combine_kernel<<<T_TOK * 128 / 256, 256, 0, stream>>>(y_part, slot_of, top_i, top_w, b2, out);
}